// Round 6
// baseline (356.293 us; speedup 1.0000x reference)
//
#include <hip/hip_runtime.h>
#include <math.h>

#define BB 256
#define VV 4096
#define DD 64

typedef __attribute__((ext_vector_type(8))) _Float16 f16x8;
typedef __attribute__((ext_vector_type(4))) float f32x4;

// ---------------------------------------------------------------------------
// Kernel 1: one block (512 threads, 8 waves) per a. Wave w owns v-rows
// [512w, 512w+512) x ALL 256 b-cols (no duplicated F reads — round-5 lesson).
// lan fragments fp16 in regs (128 VGPR). F loaded in A-fragment order with a
// 4-deep STATICALLY-NAMED prefetch pipeline (rule #20) to maximize in-flight
// vmem bytes (round-3/5 analysis: kernel is MLP x latency bound).
// No LDS / barriers in main loop. Output transposed: max0T[a*256+b].
// ---------------------------------------------------------------------------
__global__ __launch_bounds__(512, 2) void topk_sim_kernel(
    const float* __restrict__ F, const float* __restrict__ lan,
    float* __restrict__ max0T, float* __restrict__ max1T)
{
  __shared__ __align__(16) float lsm[BB * DD];   // 64 KB lan staging
  __shared__ float mrg[8][BB][2];                // 16 KB cross-wave merge
  const int t = threadIdx.x;
  const int a = blockIdx.x;
  const int wave = t >> 6;
  const int lane = t & 63;
  const int cl = lane & 15;      // A-row / B-col within 16x16 tile
  const int o  = lane >> 4;      // k-octet group

  // ---- stage lan [256][64] fp32 into LDS (coalesced, one-time) ----
  {
    const float4* s4 = (const float4*)lan;
    float4* l4 = (float4*)lsm;
#pragma unroll
    for (int j = 0; j < 8; ++j) l4[j * 512 + t] = s4[j * 512 + t];
  }
  __syncthreads();

  // ---- B fragments for all 16 column-tiles, fp16, kept in regs ----
  f16x8 bf[16][2];
#pragma unroll
  for (int ct = 0; ct < 16; ++ct)
#pragma unroll
    for (int s = 0; s < 2; ++s) {
      const float* p = lsm + (ct * 16 + cl) * DD + s * 32 + o * 8;
      f16x8 v;
#pragma unroll
      for (int e = 0; e < 8; ++e) v[e] = (_Float16)p[e];
      bf[ct][s] = v;
    }
  __syncthreads();

  float m0[16], m1[16];
#pragma unroll
  for (int ct = 0; ct < 16; ++ct) { m0[ct] = -INFINITY; m1[ct] = -INFINITY; }

  // per-lane base: row = 512*wave + chunk*16 + cl, k-octet o (both ksubs)
  const float* Fa = F + (size_t)a * VV * DD + (size_t)wave * 512 * DD
                    + cl * DD + o * 8;

#define LOADC(S0, S1, S2, S3, CH) {                                  \
    const float* _p = Fa + (size_t)(CH) * 16 * DD;                   \
    S0 = *(const float4*)(_p);      S1 = *(const float4*)(_p + 4);   \
    S2 = *(const float4*)(_p + 32); S3 = *(const float4*)(_p + 36); }

#define STAGE(S0, S1, S2, S3, CH) {                                  \
    f16x8 a0, a1;                                                    \
    a0[0] = (_Float16)S0.x; a0[1] = (_Float16)S0.y;                  \
    a0[2] = (_Float16)S0.z; a0[3] = (_Float16)S0.w;                  \
    a0[4] = (_Float16)S1.x; a0[5] = (_Float16)S1.y;                  \
    a0[6] = (_Float16)S1.z; a0[7] = (_Float16)S1.w;                  \
    a1[0] = (_Float16)S2.x; a1[1] = (_Float16)S2.y;                  \
    a1[2] = (_Float16)S2.z; a1[3] = (_Float16)S2.w;                  \
    a1[4] = (_Float16)S3.x; a1[5] = (_Float16)S3.y;                  \
    a1[6] = (_Float16)S3.z; a1[7] = (_Float16)S3.w;                  \
    if ((CH) + 4 < 32) LOADC(S0, S1, S2, S3, (CH) + 4)               \
    _Pragma("unroll")                                                \
    for (int ct = 0; ct < 16; ++ct) {                                \
      f32x4 acc = {0.f, 0.f, 0.f, 0.f};                              \
      acc = __builtin_amdgcn_mfma_f32_16x16x32_f16(a0, bf[ct][0], acc, 0, 0, 0); \
      acc = __builtin_amdgcn_mfma_f32_16x16x32_f16(a1, bf[ct][1], acc, 0, 0, 0); \
      float h1 = fmaxf(acc[0], acc[1]), q1 = fminf(acc[0], acc[1]);  \
      float h2 = fmaxf(acc[2], acc[3]), q2 = fminf(acc[2], acc[3]);  \
      float M0 = fmaxf(h1, h2);                                      \
      float M1 = fmaxf(fminf(h1, h2), fmaxf(q1, q2));                \
      float old0 = m0[ct];                                           \
      m0[ct] = fmaxf(old0, M0);                                      \
      m1[ct] = fmaxf(m1[ct], fmaxf(fminf(old0, M0), M1));            \
    }                                                                \
  }

  // ---- 4-deep statically-named pipeline over 32 chunks of 16 rows ----
  float4 p00, p01, p02, p03, p10, p11, p12, p13,
         p20, p21, p22, p23, p30, p31, p32, p33;
  LOADC(p00, p01, p02, p03, 0)
  LOADC(p10, p11, p12, p13, 1)
  LOADC(p20, p21, p22, p23, 2)
  LOADC(p30, p31, p32, p33, 3)

#pragma unroll 1
  for (int q = 0; q < 8; ++q) {
    const int ch = 4 * q;
    STAGE(p00, p01, p02, p03, ch)
    STAGE(p10, p11, p12, p13, ch + 1)
    STAGE(p20, p21, p22, p23, ch + 2)
    STAGE(p30, p31, p32, p33, ch + 3)
  }
#undef STAGE
#undef LOADC

  // ---- merge across the 4 k-octet row-groups within the wave ----
#pragma unroll
  for (int ct = 0; ct < 16; ++ct) {
#pragma unroll
    for (int off = 16; off <= 32; off <<= 1) {
      float p0 = __shfl_xor(m0[ct], off);
      float p1 = __shfl_xor(m1[ct], off);
      float n1 = fmaxf(fminf(m0[ct], p0), fmaxf(m1[ct], p1));
      m0[ct] = fmaxf(m0[ct], p0);
      m1[ct] = n1;
    }
    if (lane < 16) {
      mrg[wave][ct * 16 + lane][0] = m0[ct];
      mrg[wave][ct * 16 + lane][1] = m1[ct];
    }
  }
  __syncthreads();

  // ---- merge the 8 waves' partials; store ----
  if (t < BB) {
    float M0 = -INFINITY, M1 = -INFINITY;
#pragma unroll
    for (int w = 0; w < 8; ++w) {
      float a0 = mrg[w][t][0], a1 = mrg[w][t][1];
      float n1 = fmaxf(fminf(M0, a0), fmaxf(M1, a1));
      M0 = fmaxf(M0, a0);
      M1 = n1;
    }
    max0T[a * BB + t] = M0;
    max1T[a * BB + t] = M1;
  }
}

// ---------------------------------------------------------------------------
// Kernel 2: per row b, LSE over 511 logits, loss_b = LSE - diag.
// ---------------------------------------------------------------------------
__global__ __launch_bounds__(256) void lse_kernel(
    const float* __restrict__ max0T, const float* __restrict__ max1T,
    float* __restrict__ lossb)
{
  __shared__ float red[256];
  __shared__ float diag;
  const int b = blockIdx.x;
  const int t = threadIdx.x;     // t = a
  float x0 = max0T[t * BB + b];
  float x1 = (t == b) ? -INFINITY : max1T[t * BB + b];
  if (t == b) diag = x0;
  red[t] = fmaxf(x0, x1);
  __syncthreads();
  for (int s = 128; s > 0; s >>= 1) {
    if (t < s) red[t] = fmaxf(red[t], red[t + s]);
    __syncthreads();
  }
  float M = red[0];
  __syncthreads();
  float e = expf(x0 - M) + ((t == b) ? 0.0f : expf(x1 - M));
  red[t] = e;
  __syncthreads();
  for (int s = 128; s > 0; s >>= 1) {
    if (t < s) red[t] = red[t] + red[t + s];
    __syncthreads();
  }
  if (t == 0) lossb[b] = logf(red[0]) + M - diag;
}

__global__ __launch_bounds__(256) void mean_kernel(
    const float* __restrict__ lossb, float* __restrict__ out)
{
  __shared__ float red[256];
  const int t = threadIdx.x;
  red[t] = lossb[t];
  __syncthreads();
  for (int s = 128; s > 0; s >>= 1) {
    if (t < s) red[t] += red[t + s];
    __syncthreads();
  }
  if (t == 0) out[0] = red[0] * (1.0f / 256.0f);
}

extern "C" void kernel_launch(void* const* d_in, const int* in_sizes, int n_in,
                              void* d_out, int out_size, void* d_ws, size_t ws_size,
                              hipStream_t stream) {
  const float* F   = (const float*)d_in[0];   // fusion_fs [256,4096,64] fp32
  const float* lan = (const float*)d_in[1];   // lan_fs    [256,1,64]   fp32
  float* ws = (float*)d_ws;
  float* max0T = ws;                // [256*256]
  float* max1T = ws + 65536;        // [256*256]
  float* lossb = ws + 131072;       // [256]

  topk_sim_kernel<<<256, 512, 0, stream>>>(F, lan, max0T, max1T);
  lse_kernel<<<256, 256, 0, stream>>>(max0T, max1T, lossb);
  mean_kernel<<<1, 256, 0, stream>>>(lossb, (float*)d_out);
}